// Round 7
// baseline (158.883 us; speedup 1.0000x reference)
//
#include <hip/hip_runtime.h>
#include <cmath>

#define TW 32
#define SUB 32            // output rows per sub-tile
#define NSUB 2
#define TH (SUB * NSUB)   // 64 output rows per block
#define HR (SUB + 10)     // 42-row sliding LDS window
#define NT 256
#define IMG 512
#define SSIM_C1 1e-4f
#define SSIM_C2 9e-4f

struct GaussWin { float g[11]; };

typedef float v2f __attribute__((ext_vector_type(2)));

// Native packed fp32: clang/LLVM selects v_pk_fma_f32 for <2 x float> on
// gfx90a+ (HasPackedFP32Ops).
__device__ __forceinline__ v2f pk_fma(v2f a, v2f b, v2f c) {
    return __builtin_elementwise_fma(a, b, c);
}

// R7: sliding-window, NSUB=2. R6 (NSUB=4, 3072 blocks) proved the window
// cuts issued work to the session low (dur*busy ~28 us-equiv) but starved
// the CUs: 12 blocks/CU of total work + 8 barrier phases/block -> busy 45%.
// NSUB=2 keeps the window mechanism (halo ratio 74/64=1.16, fixed cost
// halved vs R2) at 6144 blocks (24/CU of work) and half R6's barrier
// cadence. LDS 21.5 KB -> 7 blocks/CU, NT=256, VGPR ~52 (no prefetch:
// +48 VGPR would drop the HW wave cap to 4/SIMD and kill residency).
__device__ __forceinline__ void h_pass_rows(const float* __restrict__ xp,
                                            const float* __restrict__ yp,
                                            int tx0, int gy0, int slot0, int nrows,
                                            const v2f* __restrict__ w2,
                                            float4* __restrict__ s_h, int tid) {
    constexpr int WI[11] = {0,1,2,3,4,5,4,3,2,1,0};
    if (tid < nrows * 4) {
        const int r = tid >> 2;
        const int cs = (tid & 3) * 8;
        const int gy = gy0 + r;
        const int slot = slot0 + r;
        const float* xrow = xp + gy * IMG;
        const float* yrow = yp + gy * IMG;
        const int c0 = tx0 + cs - 8;

        // Per-strip fast-path guard: row in-bounds AND col window
        // [c0, c0+24) within [0,512).
        const bool fast = ((unsigned)gy < IMG) & ((unsigned)c0 <= (unsigned)(IMG - 24));

        float4 fx[6], fy[6];
        if (fast) {
            #pragma unroll
            for (int q = 0; q < 6; q++) {
                fx[q] = *(const float4*)(xrow + c0 + 4 * q);
                fy[q] = *(const float4*)(yrow + c0 + 4 * q);
            }
        } else {
            const bool rowok = ((unsigned)gy < IMG);
            #pragma unroll
            for (int q = 0; q < 6; q++) {
                int col = c0 + 4 * q;
                fx[q] = make_float4(0.f, 0.f, 0.f, 0.f);
                fy[q] = make_float4(0.f, 0.f, 0.f, 0.f);
                if (rowok && (unsigned)col <= (unsigned)(IMG - 4)) {
                    fx[q] = *(const float4*)(xrow + col);
                    fy[q] = *(const float4*)(yrow + col);
                }
            }
        }
        float vxa[24], vya[24];
        #pragma unroll
        for (int q = 0; q < 6; q++) {
            vxa[4*q+0]=fx[q].x; vxa[4*q+1]=fx[q].y; vxa[4*q+2]=fx[q].z; vxa[4*q+3]=fx[q].w;
            vya[4*q+0]=fy[q].x; vya[4*q+1]=fy[q].y; vya[4*q+2]=fy[q].z; vya[4*q+3]=fy[q].w;
        }

        // Streaming tap-major conv over the two packed accumulators.
        v2f amu[8], a2[8];
        #pragma unroll
        for (int j = 0; j < 8; j++) { amu[j]=(v2f){0.f,0.f}; a2[j]=(v2f){0.f,0.f}; }
        #pragma unroll
        for (int k = 0; k < 18; k++) {
            float xv = vxa[k + 3], yv = vya[k + 3];
            v2f xy = (v2f){xv, yv};
            v2f p2 = xy * xy;                     // (x^2, y^2)
            v2f zw = (v2f){p2.x + p2.y, xv * yv}; // (x^2+y^2, x*y)
            const int jlo = (k - 10 > 0) ? (k - 10) : 0;
            const int jhi = (k < 7) ? k : 7;
            #pragma unroll
            for (int j = jlo; j <= jhi; j++) {
                v2f w = w2[WI[k - j]];
                amu[j] = pk_fma(xy, w, amu[j]);
                a2[j]  = pk_fma(zw, w, a2[j]);
            }
        }
        const int quad = cs & 24;
        const int base0 = cs + 2 * (cs >> 3) + 5 * slot;
        #pragma unroll
        for (int j = 0; j < 8; j++) {
            int pc = quad | ((base0 + j) & 7);
            s_h[slot * TW + pc] = make_float4(amu[j].x, amu[j].y, a2[j].x, a2[j].y);
        }
    }
}

__launch_bounds__(NT, 4)
__global__ void ssim_tile_kernel(const float* __restrict__ x,
                                 const float* __restrict__ y,
                                 const float* __restrict__ conf,
                                 float* __restrict__ partials,
                                 float* __restrict__ out,
                                 int use_ws, float scale,
                                 GaussWin W) {
    __shared__ float4 s_h[HR * TW];     // 21504 B  (mu_x, mu_y, s2, sxy)
    __shared__ float  s_red[4];         // ~21.6 KB total -> 7 blocks/CU

    const int tid = threadIdx.x;
    const int plane = blockIdx.z;              // b*3 + c
    const int tx0 = blockIdx.x * TW;
    const int ty0 = blockIdx.y * TH;
    const float* xp = x + plane * (IMG * IMG);
    const float* yp = y + plane * (IMG * IMG);
    const int cbase = (plane / 3) * (IMG * IMG);

    // Gaussian symmetric: g[k] == g[10-k] bitwise. 6 distinct packed weights.
    constexpr int WI[11] = {0,1,2,3,4,5,4,3,2,1,0};
    v2f w2[6];
    #pragma unroll
    for (int i = 0; i < 6; i++) w2[i] = (v2f){W.g[i], W.g[i]};

    // Phase-2 addressing: slot-window layout is identical for all sub-tiles,
    // so the 8 swizzle bases (period 8: 5*8 == 0 mod 8) are computed ONCE.
    const int c   = tid & 31;
    const int r0c = (tid >> 5) * 4;           // 8 groups x 4 rows = 32 rows
    const int cquad = c & 24;
    const int cb0 = c + 2 * (c >> 3) + 5 * r0c;
    int bidx[8];
    #pragma unroll
    for (int p = 0; p < 8; p++) {
        bidx[p] = r0c * TW + (cquad | ((cb0 + 5 * p) & 7));
    }

    float lsum = 0.f;
    float4 st0, st1;                          // 10-row overlap stash

    #pragma unroll
    for (int s = 0; s < NSUB; s++) {
        if (s == 0) {
            // Window rows [ty0-5, ty0+36] -> slots 0..41 (168 strips).
            h_pass_rows(xp, yp, tx0, ty0 - 5, 0, HR, w2, s_h, tid);
        } else {
            __syncthreads();  // P2(s-1) reads + stash reads complete
            // Stash write: slots 32..41 of old window -> slots 0..9 of new
            // (raw region copy; swizzle phases align: 5*32 == 0 mod 8).
            ((float4*)s_h)[tid] = st0;
            if (tid < 64) ((float4*)s_h)[256 + tid] = st1;
            // Compute the 32 new h-rows -> slots 10..41 (128 strips).
            h_pass_rows(xp, yp, tx0, ty0 + SUB * s + 5, 10, SUB, w2, s_h, tid);
        }

        // conf for this sub-tile (global load overlaps the barrier).
        float cf[4];
        #pragma unroll
        for (int j = 0; j < 4; j++) {
            cf[j] = conf[cbase + (ty0 + SUB * s + r0c + j) * IMG + tx0 + c];
        }
        __syncthreads();

        // ---- Phase 2: vertical pass, 4 outputs/thread ----
        v2f amu[4], a2[4];
        #pragma unroll
        for (int j = 0; j < 4; j++) { amu[j]=(v2f){0.f,0.f}; a2[j]=(v2f){0.f,0.f}; }
        #pragma unroll
        for (int t = 0; t < 14; t++) {
            float4 h4 = s_h[bidx[t & 7] + t * TW];   // t*TW folds to offset imm
            v2f hmu = (v2f){h4.x, h4.y};
            v2f h2  = (v2f){h4.z, h4.w};
            #pragma unroll
            for (int j = 0; j < 4; j++) {
                int k = t - j;                        // constant post-unroll
                if (k >= 0 && k <= 10) {
                    v2f w = w2[WI[k]];
                    amu[j] = pk_fma(hmu, w, amu[j]);
                    a2[j]  = pk_fma(h2, w, a2[j]);
                }
            }
        }

        // Stash-read the 10 overlap rows (slots 32..41) for the next window.
        if (s + 1 < NSUB) {
            st0 = ((const float4*)s_h)[32 * TW + tid];
            if (tid < 64) st1 = ((const float4*)s_h)[40 * TW + tid];
        }

        // ---- Epilogue: SSIM + conf weighting ----
        #pragma unroll
        for (int j = 0; j < 4; j++) {
            float mu_x = amu[j].x, mu_y = amu[j].y;
            v2f prod = amu[j] * amu[j];           // (mu_x^2, mu_y^2)
            float mu_xy = mu_x * mu_y;
            float musq  = prod.x + prod.y;
            float sigsum = a2[j].x - musq;        // sigma_x^2 + sigma_y^2
            float sigxy  = a2[j].y - mu_xy;
            float num = fmaf(2.f, mu_xy, SSIM_C1) * fmaf(2.f, sigxy, SSIM_C2);
            float den = (musq + SSIM_C1) * (sigsum + SSIM_C2);
            float ssim = num * __builtin_amdgcn_rcpf(den);   // den > 0
            float loss = fminf(fmaxf(1.f - ssim, 0.f), 1.f);
            lsum = fmaf(loss, cf[j], lsum);
        }
    }

    // ---- Block reduction ----
    #pragma unroll
    for (int off = 32; off; off >>= 1) lsum += __shfl_down(lsum, off, 64);
    if ((tid & 63) == 0) s_red[tid >> 6] = lsum;
    __syncthreads();
    if (tid == 0) {
        float t = s_red[0] + s_red[1] + s_red[2] + s_red[3];
        if (use_ws) {
            partials[blockIdx.x + gridDim.x * (blockIdx.y + gridDim.y * blockIdx.z)] = t;
        } else {
            atomicAdd(out, t * scale);
        }
    }
}

// Single-block reduce: writes out[0] directly (no memset, no atomics).
__global__ void reduce_kernel(const float* __restrict__ partials, int n,
                              float* __restrict__ out, float scale) {
    __shared__ float s_red[16];
    float s = 0.f;
    const float4* p4 = (const float4*)partials;
    const int n4 = n >> 2;
    for (int i = threadIdx.x; i < n4; i += 1024) {
        float4 v = p4[i];
        s += (v.x + v.y) + (v.z + v.w);
    }
    for (int i = (n4 << 2) + threadIdx.x; i < n; i += 1024) s += partials[i];
    #pragma unroll
    for (int off = 32; off; off >>= 1) s += __shfl_down(s, off, 64);
    if ((threadIdx.x & 63) == 0) s_red[threadIdx.x >> 6] = s;
    __syncthreads();
    if (threadIdx.x == 0) {
        float t = 0.f;
        #pragma unroll
        for (int i = 0; i < 16; i++) t += s_red[i];
        out[0] = t * scale;
    }
}

extern "C" void kernel_launch(void* const* d_in, const int* in_sizes, int n_in,
                              void* d_out, int out_size, void* d_ws, size_t ws_size,
                              hipStream_t stream) {
    const float* x    = (const float*)d_in[0];
    const float* y    = (const float*)d_in[1];
    const float* conf = (const float*)d_in[2];
    float* out = (float*)d_out;
    float* partials = (float*)d_ws;

    // Gaussian window, computed like the reference: float64 exp + normalize, cast f32
    GaussWin W;
    {
        double gd[11], s = 0.0;
        for (int i = 0; i < 11; i++) { gd[i] = exp(-((i - 5) * (i - 5)) / 4.5); s += gd[i]; }
        for (int i = 0; i < 11; i++) W.g[i] = (float)(gd[i] / s);
    }

    const int B = 16, C = 3;
    const float scale = 1.0f / (float)(B * C * IMG * IMG);
    dim3 grid(IMG / TW, IMG / TH, B * C);                   // 16 x 8 x 48 = 6144 blocks
    const int nblocks = (IMG / TW) * (IMG / TH) * B * C;
    const int use_ws = (ws_size >= (size_t)nblocks * sizeof(float)) ? 1 : 0;

    if (!use_ws) {
        // fallback: atomic accumulation into d_out (poisoned before each call)
        hipMemsetAsync(d_out, 0, sizeof(float), stream);
    }
    ssim_tile_kernel<<<grid, NT, 0, stream>>>(x, y, conf, partials, out, use_ws, scale, W);
    if (use_ws) {
        reduce_kernel<<<1, 1024, 0, stream>>>(partials, nblocks, out, scale);
    }
}

// Round 8
// 157.143 us; speedup vs baseline: 1.0111x; 1.0111x over previous
//
#include <hip/hip_runtime.h>
#include <cmath>

#define TW 32
#define TH 48
#define HR (TH + 10)     // 58 rows of h-pass results
#define NT 256
#define IMG 512
#define SSIM_C1 1e-4f
#define SSIM_C2 9e-4f

struct GaussWin { float g[11]; };

typedef float v2f __attribute__((ext_vector_type(2)));

// Native packed fp32: clang/LLVM selects v_pk_fma_f32 for <2 x float> on
// gfx90a+ (HasPackedFP32Ops).
__device__ __forceinline__ v2f pk_fma(v2f a, v2f b, v2f c) {
    return __builtin_elementwise_fma(a, b, c);
}

// R8 = R0's geometry x R2's algebra.
// Four-field formulation (R2, proven -24% work): conv pairs A=(x,y),
// B=(x^2+y^2, x*y) -> 2 pk_fma per output-tap in both passes; h-result is
// one float4 -> LDS 29.7 KB at TH=48 -> 5 blocks/CU.
// TH=48 (R0, proven 70% busy at 4 blk/CU): phase-1 is a SINGLE round
// (232 strips < 256 threads; R3's TH=64 strided second trip serialized),
// phase-2 reads 16 rows for 6 outputs (2.67/out vs R2's 3.5).
// Sliding-window variants (R6/R7) are dead: the compiler's vmcnt(0) drain
// before s_barrier serializes mid-block load phases.
__launch_bounds__(NT, 4)
__global__ void ssim_tile_kernel(const float* __restrict__ x,
                                 const float* __restrict__ y,
                                 const float* __restrict__ conf,
                                 float* __restrict__ partials,
                                 float* __restrict__ out,
                                 int use_ws, float scale,
                                 GaussWin W) {
    __shared__ float4 s_h[HR * TW];     // 29696 B  (mu_x, mu_y, s2, sxy)
    __shared__ float  s_red[4];         // ~29.7 KB total -> 5 blocks/CU

    const int tid = threadIdx.x;
    const int plane = blockIdx.z;              // b*3 + c
    const int tx0 = blockIdx.x * TW;
    const int ty0 = blockIdx.y * TH;
    const int pbase = plane * (IMG * IMG);
    const int cbase = (plane / 3) * (IMG * IMG);

    // Gaussian symmetric: g[k] == g[10-k] bitwise. 6 distinct packed weights.
    constexpr int WI[11] = {0,1,2,3,4,5,4,3,2,1,0};
    v2f w2[6];
    #pragma unroll
    for (int i = 0; i < 6; i++) w2[i] = (v2f){W.g[i], W.g[i]};

    // Interior blocks touch no image border anywhere in the halo window.
    // TH=48: rows [ty0-5, ty0+52] in-bounds iff 1 <= by <= 9 (grid-y = 11).
    const bool interior = (blockIdx.x >= 1) & (blockIdx.x <= 14) &
                          (blockIdx.y >= 1) & (blockIdx.y <= 9);

    // ---- Phase 1: horizontal pass, direct from global ----
    // 58 rows x 4 col-groups = 232 strips, one per thread, ONE round.
    // Strip = 8 output cols; reads 6 aligned float4s per array covering cols
    // [cs-8, cs+16); elements 3..20 are the 18 taps. 16B-aligned reads are
    // fully in- or out-of-bounds -> exact zero padding.
    if (tid < HR * 4) {
        const int r = tid >> 2;
        const int cs = (tid & 3) * 8;
        const int gy = ty0 - 5 + r;
        const float* xrow = x + pbase + gy * IMG;
        const float* yrow = y + pbase + gy * IMG;
        const int c0 = tx0 + cs - 8;

        float4 fx[6], fy[6];
        if (interior) {
            #pragma unroll
            for (int q = 0; q < 6; q++) {
                fx[q] = *(const float4*)(xrow + c0 + 4 * q);
                fy[q] = *(const float4*)(yrow + c0 + 4 * q);
            }
        } else {
            const bool rowok = ((unsigned)gy < IMG);
            #pragma unroll
            for (int q = 0; q < 6; q++) {
                int col = c0 + 4 * q;
                fx[q] = make_float4(0.f, 0.f, 0.f, 0.f);
                fy[q] = make_float4(0.f, 0.f, 0.f, 0.f);
                if (rowok && (unsigned)col <= (unsigned)(IMG - 4)) {
                    fx[q] = *(const float4*)(xrow + col);
                    fy[q] = *(const float4*)(yrow + col);
                }
            }
        }
        float vxa[24], vya[24];
        #pragma unroll
        for (int q = 0; q < 6; q++) {
            vxa[4*q+0]=fx[q].x; vxa[4*q+1]=fx[q].y; vxa[4*q+2]=fx[q].z; vxa[4*q+3]=fx[q].w;
            vya[4*q+0]=fy[q].x; vya[4*q+1]=fy[q].y; vya[4*q+2]=fy[q].z; vya[4*q+3]=fy[q].w;
        }

        // Streaming tap-major conv over the two packed accumulators.
        v2f amu[8], a2[8];
        #pragma unroll
        for (int j = 0; j < 8; j++) { amu[j]=(v2f){0.f,0.f}; a2[j]=(v2f){0.f,0.f}; }
        #pragma unroll
        for (int k = 0; k < 18; k++) {
            float xv = vxa[k + 3], yv = vya[k + 3];
            v2f xy = (v2f){xv, yv};
            v2f p2 = xy * xy;                     // (x^2, y^2)
            v2f zw = (v2f){p2.x + p2.y, xv * yv}; // (x^2+y^2, x*y)
            const int jlo = (k - 10 > 0) ? (k - 10) : 0;
            const int jhi = (k < 7) ? k : 7;
            #pragma unroll
            for (int j = jlo; j <= jhi; j++) {
                v2f w = w2[WI[k - j]];
                amu[j] = pk_fma(xy, w, amu[j]);
                a2[j]  = pk_fma(zw, w, a2[j]);
            }
        }
        const int quad = cs & 24;
        const int base0 = cs + 2 * (cs >> 3) + 5 * r;
        #pragma unroll
        for (int j = 0; j < 8; j++) {
            int pc = quad | ((base0 + j) & 7);
            s_h[r * TW + pc] = make_float4(amu[j].x, amu[j].y, a2[j].x, a2[j].y);
        }
    }

    // Prefetch conf (consumed in epilogue) before the barrier.
    // by=10 tail rows (gy >= 512) get cf=0 and contribute exactly 0
    // (den >= C1*C2 > 0, finite loss) -- no other guard needed.
    const int c  = tid & 31;
    const int r0 = (tid >> 5) * 6;            // 8 groups x 6 rows = 48 rows
    float cf[6];
    #pragma unroll
    for (int j = 0; j < 6; j++) {
        int gy = ty0 + r0 + j;
        cf[j] = (gy < IMG) ? conf[cbase + gy * IMG + tx0 + c] : 0.f;
    }
    __syncthreads();

    // ---- Phase 2: vertical pass, 6 vertically-adjacent outputs per thread ----
    // Swizzled col index pc(t) has period 8 in t (5*8 == 0 mod 8): precompute
    // the 8 base indices; t*TW folds into the ds_read offset immediate
    // (max 15*512 = 7680 B < 64 KiB) -> zero per-iteration address VALU.
    v2f amu[6], a2[6];
    #pragma unroll
    for (int j = 0; j < 6; j++) { amu[j]=(v2f){0.f,0.f}; a2[j]=(v2f){0.f,0.f}; }

    const int cquad = c & 24;
    const int cb0 = c + 2 * (c >> 3) + 5 * r0;
    int bidx[8];
    #pragma unroll
    for (int p = 0; p < 8; p++) {
        bidx[p] = r0 * TW + (cquad | ((cb0 + 5 * p) & 7));
    }
    #pragma unroll
    for (int t = 0; t < 16; t++) {
        float4 h4 = s_h[bidx[t & 7] + t * TW];
        v2f hmu = (v2f){h4.x, h4.y};
        v2f h2  = (v2f){h4.z, h4.w};
        #pragma unroll
        for (int j = 0; j < 6; j++) {
            int k = t - j;                    // constant post-unroll
            if (k >= 0 && k <= 10) {
                v2f w = w2[WI[k]];
                amu[j] = pk_fma(hmu, w, amu[j]);
                a2[j]  = pk_fma(h2, w, a2[j]);
            }
        }
    }

    // ---- Epilogue: SSIM + conf weighting + accumulate ----
    float lsum = 0.f;
    #pragma unroll
    for (int j = 0; j < 6; j++) {
        float mu_x = amu[j].x, mu_y = amu[j].y;
        v2f prod = amu[j] * amu[j];           // (mu_x^2, mu_y^2), packed
        float mu_xy = mu_x * mu_y;
        float musq  = prod.x + prod.y;        // mu_x^2 + mu_y^2
        float sigsum = a2[j].x - musq;        // sigma_x^2 + sigma_y^2
        float sigxy  = a2[j].y - mu_xy;
        float num = fmaf(2.f, mu_xy, SSIM_C1) * fmaf(2.f, sigxy, SSIM_C2);
        float den = (musq + SSIM_C1) * (sigsum + SSIM_C2);
        float ssim = num * __builtin_amdgcn_rcpf(den);   // den >= C1*C2 > 0
        float loss = fminf(fmaxf(1.f - ssim, 0.f), 1.f);
        lsum = fmaf(loss, cf[j], lsum);
    }

    // ---- Block reduction ----
    #pragma unroll
    for (int off = 32; off; off >>= 1) lsum += __shfl_down(lsum, off, 64);
    if ((tid & 63) == 0) s_red[tid >> 6] = lsum;
    __syncthreads();
    if (tid == 0) {
        float t = s_red[0] + s_red[1] + s_red[2] + s_red[3];
        if (use_ws) {
            partials[blockIdx.x + gridDim.x * (blockIdx.y + gridDim.y * blockIdx.z)] = t;
        } else {
            atomicAdd(out, t * scale);
        }
    }
}

// Single-block reduce: writes out[0] directly (no memset, no atomics).
__global__ void reduce_kernel(const float* __restrict__ partials, int n,
                              float* __restrict__ out, float scale) {
    __shared__ float s_red[16];
    float s = 0.f;
    const float4* p4 = (const float4*)partials;
    const int n4 = n >> 2;
    for (int i = threadIdx.x; i < n4; i += 1024) {
        float4 v = p4[i];
        s += (v.x + v.y) + (v.z + v.w);
    }
    for (int i = (n4 << 2) + threadIdx.x; i < n; i += 1024) s += partials[i];
    #pragma unroll
    for (int off = 32; off; off >>= 1) s += __shfl_down(s, off, 64);
    if ((threadIdx.x & 63) == 0) s_red[threadIdx.x >> 6] = s;
    __syncthreads();
    if (threadIdx.x == 0) {
        float t = 0.f;
        #pragma unroll
        for (int i = 0; i < 16; i++) t += s_red[i];
        out[0] = t * scale;
    }
}

extern "C" void kernel_launch(void* const* d_in, const int* in_sizes, int n_in,
                              void* d_out, int out_size, void* d_ws, size_t ws_size,
                              hipStream_t stream) {
    const float* x    = (const float*)d_in[0];
    const float* y    = (const float*)d_in[1];
    const float* conf = (const float*)d_in[2];
    float* out = (float*)d_out;
    float* partials = (float*)d_ws;

    // Gaussian window, computed like the reference: float64 exp + normalize, cast f32
    GaussWin W;
    {
        double gd[11], s = 0.0;
        for (int i = 0; i < 11; i++) { gd[i] = exp(-((i - 5) * (i - 5)) / 4.5); s += gd[i]; }
        for (int i = 0; i < 11; i++) W.g[i] = (float)(gd[i] / s);
    }

    const int B = 16, C = 3;
    const float scale = 1.0f / (float)(B * C * IMG * IMG);
    const int gy_blocks = (IMG + TH - 1) / TH;              // 11 (last block masked)
    dim3 grid(IMG / TW, gy_blocks, B * C);                  // 16 x 11 x 48 = 8448 blocks
    const int nblocks = (IMG / TW) * gy_blocks * B * C;
    const int use_ws = (ws_size >= (size_t)nblocks * sizeof(float)) ? 1 : 0;

    if (!use_ws) {
        // fallback: atomic accumulation into d_out (poisoned before each call)
        hipMemsetAsync(d_out, 0, sizeof(float), stream);
    }
    ssim_tile_kernel<<<grid, NT, 0, stream>>>(x, y, conf, partials, out, use_ws, scale, W);
    if (use_ws) {
        reduce_kernel<<<1, 1024, 0, stream>>>(partials, nblocks, out, scale);
    }
}